// Round 14
// baseline (2572.888 us; speedup 1.0000x reference)
//
#include <hip/hip_runtime.h>

#define T_STEPS 1000
#define BATCH   256
#define NHID    200
#define ROWF    200      // floats per LDS row (800 B, 16B-aligned)
#define BETA_C  0.85f
#define THR_C   1.0f

// WT2 row i (source neuron i) holds at float offset lo*4+k (lo<50,k<4):
// Wrec[(lo+50k)][i]. Lane lo reads ONE ds_read_b128 per firing source i,
// yielding weights for outputs {lo, lo+50, lo+100, lo+150}.
//
// 8 waves per batch element. Wave pair (w, w+4) splits source word w into
// low/high 25-bit halves (~3.5 firing each -> one 4-wide gather trip, one
// LDS wait). Both halves atomicAdd (ds_add_f32) their component partials
// into part[comp][word][lane]; each slot gets exactly TWO contributions,
// and 2-operand IEEE addition is commutative -> result is deterministic
// despite the race. Waves 0-3 (readers) own output words: read partials,
// re-zero them (same-wave DS ordering + BAR2's lgkm drain makes this safe
// with no extra barrier), reduce ((p0+p1)+p2)+p3, update their 50 neurons,
// ballot, store. High waves get their half-mask from LDS. 2 barriers/step,
// lgkm-only (spike stores stay fire-and-forget). cur2 via second kernel.

#define BARRIER_LGKM \
    asm volatile("s_waitcnt lgkmcnt(0)\n\ts_barrier" ::: "memory");

__launch_bounds__(512, 1)
__global__ void rsnn_kernel(const float* __restrict__ X,
                            const float* __restrict__ W1,
                            const float* __restrict__ b1,
                            const float* __restrict__ Wrec,
                            const float* __restrict__ brec,
                            float* __restrict__ out_spk) {
#pragma clang fp contract(off)
    __shared__ float              WT2[NHID * ROWF];   // 160,000 B
    __shared__ float              part[4][4][50];     //   3,200 B [comp][word][lane]
    __shared__ unsigned long long mask_lds[4];        //      32 B

    const int tid = threadIdx.x;
    const int l   = tid & 63;            // lane
    const int wv  = tid >> 6;            // wave 0..7
    const int w   = wv & 3;              // source/output word id
    const int hi  = wv >> 2;             // 0 = low half (+reader), 1 = high half
    const int b   = blockIdx.x;

    // ---- stage Wrec (permuted transpose); zero part + masks ----
    for (int idx = tid; idx < NHID * NHID; idx += 512) {
        int r  = idx / NHID;             // Wrec row  (output neuron)
        int i  = idx - r * NHID;         // Wrec col  (source neuron)
        int lo = r % 50, k = r / 50;
        WT2[i * ROWF + lo * 4 + k] = Wrec[idx];
    }
    for (int idx = tid; idx < 800; idx += 512) ((float*)part)[idx] = 0.f;
    if (tid < 4) mask_lds[tid] = 0ull;
    __syncthreads();

    const int lc = (l < 50) ? l : 49;    // lanes 50-63 duplicate lane 49
    const int oc = 50 * w + lc;          // reader wave's output neuron
    const float w10 = W1[oc * 3 + 0], w11 = W1[oc * 3 + 1], w12 = W1[oc * 3 + 2];
    const float b1j = b1[oc], brj = brec[oc];

    float mem = 0.f;
    unsigned long long bm = 0;           // reader's own-word ballot

    const float* xp = X + (size_t)b * 3;
    float x0 = xp[0], x1 = xp[1], x2 = xp[2];

    const float* ldsrow  = WT2 + (size_t)lc * 4;
    const int    gbase   = 50 * w + 25 * hi;   // first source row of my half
    float*       spk_out = out_spk + (size_t)b * NHID + 50 * w + lc;

#define REC_WORD(MASK, BASE)                                                          \
    {                                                                                 \
        unsigned long long m = (MASK);                                                \
        while (m) {                                                                   \
            int i0 = __builtin_ctzll(m); m &= m - 1;                                  \
            bool h1 = m != 0; int i1 = h1 ? __builtin_ctzll(m) : i0; if (h1) m &= m - 1; \
            bool h2 = m != 0; int i2 = h2 ? __builtin_ctzll(m) : i0; if (h2) m &= m - 1; \
            bool h3 = m != 0; int i3 = h3 ? __builtin_ctzll(m) : i0; if (h3) m &= m - 1; \
            const float4 v0 = *(const float4*)(ldsrow + (i0 + (BASE)) * ROWF);        \
            const float4 v1 = *(const float4*)(ldsrow + (i1 + (BASE)) * ROWF);        \
            const float4 v2 = *(const float4*)(ldsrow + (i2 + (BASE)) * ROWF);        \
            const float4 v3 = *(const float4*)(ldsrow + (i3 + (BASE)) * ROWF);        \
            pr0 += v0.x; pr1 += v0.y; pr2 += v0.z; pr3 += v0.w;                       \
            if (h1) { pr0 += v1.x; pr1 += v1.y; pr2 += v1.z; pr3 += v1.w; }           \
            if (h2) { pr0 += v2.x; pr1 += v2.y; pr2 += v2.z; pr3 += v2.w; }           \
            if (h3) { pr0 += v3.x; pr1 += v3.y; pr2 += v3.z; pr3 += v3.w; }           \
        }                                                                             \
    }

    for (int t = 0; t < T_STEPS; ++t) {
        // ---- A: obtain my 25-bit half of word w's spike mask ----
        unsigned long long mfull;
        if (hi) {
            unsigned long long v = mask_lds[w];   // uniform broadcast read
            unsigned a0 = __builtin_amdgcn_readfirstlane((unsigned)v);
            unsigned a1 = __builtin_amdgcn_readfirstlane((unsigned)(v >> 32));
            mfull = (((unsigned long long)a1) << 32) | a0;
        } else {
            mfull = bm;
        }
        unsigned long long mh = hi ? (mfull >> 25) : (mfull & 0x1FFFFFFull);

        // ---- gather my half (~3.5 firing: usually one trip, one wait) ----
        float pr0 = 0.f, pr1 = 0.f, pr2 = 0.f, pr3 = 0.f;
        REC_WORD(mh, gbase)

        // ---- merge: 2 atomic contributions/slot, order-independent ----
        if (l < 50) {
            atomicAdd(&part[0][w][l], pr0);
            atomicAdd(&part[1][w][l], pr1);
            atomicAdd(&part[2][w][l], pr2);
            atomicAdd(&part[3][w][l], pr3);
        }
        BARRIER_LGKM   // BAR1: all partials merged

        // ---- C: readers consume, re-zero, update, publish ----
        if (hi == 0) {
            int   tn  = (t + 1 < T_STEPS) ? t + 1 : t;
            float nx0 = xp[(size_t)tn * BATCH * 3 + 0];
            float nx1 = xp[(size_t)tn * BATCH * 3 + 1];
            float nx2 = xp[(size_t)tn * BATCH * 3 + 2];

            float p0 = part[w][0][lc], p1 = part[w][1][lc];
            float p2 = part[w][2][lc], p3 = part[w][3][lc];
            if (l < 50) {   // re-zero for next step (same-wave DS ordering)
                part[w][0][l] = 0.f; part[w][1][l] = 0.f;
                part[w][2][l] = 0.f; part[w][3][l] = 0.f;
            }
            float rec = ((p0 + p1) + p2) + p3;

            float c1 = fmaf(x2, w12, fmaf(x1, w11, x0 * w10)) + b1j;
            float ba = ((BETA_C * mem + c1) + rec) + brj;
            float nm = (mem > THR_C) ? 0.f : ba;
            float sp = (nm > THR_C) ? 1.f : 0.f;
            mem = nm;

            if (l < 50)
                spk_out[(size_t)t * BATCH * NHID] = sp;   // fire-and-forget
            bm = __ballot((l < 50) && (sp > 0.5f));
            if (l == 0) mask_lds[w] = bm;

            x0 = nx0; x1 = nx1; x2 = nx2;
        }
        BARRIER_LGKM   // BAR2: zeros + mask published
    }
#undef REC_WORD
}

// cur2[t,b] = sum_j spk[t,b,j]*W2[j] + b2 — recomputed from stored spikes
// (L3-resident). Terminal output: tree reduction order is safe.
__launch_bounds__(256)
__global__ void cur2_kernel(const float* __restrict__ spk,
                            const float* __restrict__ W2,
                            const float* __restrict__ b2,
                            float* __restrict__ out) {
    const int lane = threadIdx.x & 63;
    const int wid  = (int)((blockIdx.x * blockDim.x + threadIdx.x) >> 6);
    const int nw   = (int)((gridDim.x * blockDim.x) >> 6);

    float4 w2v = {0.f, 0.f, 0.f, 0.f};
    if (lane < 50) w2v = *(const float4*)(W2 + lane * 4);
    const float b2v = b2[0];

    for (int p = wid; p < T_STEPS * BATCH; p += nw) {
        float4 sv = {0.f, 0.f, 0.f, 0.f};
        if (lane < 50) sv = *(const float4*)(spk + (size_t)p * NHID + lane * 4);
        float a = fmaf(sv.w, w2v.w, fmaf(sv.z, w2v.z,
                  fmaf(sv.y, w2v.y, sv.x * w2v.x)));
#pragma unroll
        for (int o = 32; o >= 1; o >>= 1) a += __shfl_xor(a, o);
        if (lane == 0) out[p] = a + b2v;   // p = t*BATCH + b
    }
}

extern "C" void kernel_launch(void* const* d_in, const int* in_sizes, int n_in,
                              void* d_out, int out_size, void* d_ws, size_t ws_size,
                              hipStream_t stream) {
    const float* X    = (const float*)d_in[0];
    const float* W1   = (const float*)d_in[1];
    const float* b1   = (const float*)d_in[2];
    const float* Wrec = (const float*)d_in[3];
    const float* brec = (const float*)d_in[4];
    const float* W2   = (const float*)d_in[5];
    const float* b2   = (const float*)d_in[6];

    float* out_cur2 = (float*)d_out;                            // [T,B,1] flat
    float* out_spk  = (float*)d_out + (size_t)T_STEPS * BATCH;  // [T,B,200] flat

    rsnn_kernel<<<BATCH, 512, 0, stream>>>(X, W1, b1, Wrec, brec, out_spk);
    cur2_kernel<<<1024, 256, 0, stream>>>(out_spk, W2, b2, out_cur2);
}

// Round 15
// 563.506 us; speedup vs baseline: 4.5659x; 4.5659x over previous
//
#include <hip/hip_runtime.h>

#define T_STEPS 1000
#define BATCH   256
#define NHID    200
#define ROWF    200      // floats per LDS row (800 B, 16B-aligned)
#define BETA_C  0.85f
#define THR_C   1.0f

// WT2 row i (source neuron i) holds at float offset lo*4+k (lo<50,k<4):
// Wrec[(lo+50k)][i]. Lane lo reads ONE ds_read_b128 per firing source i,
// yielding weights for outputs {lo, lo+50, lo+100, lo+150}.
//
// 4 waves per batch element; wave w gathers source word w (~7 firing) into
// component partials pr0..pr3 and owns output word w (round 13 structure).
// NEW: parity-transposed exchange -> ONE barrier per step.
//   even t: write part[c][w][l], read part[w][s][lc]
//   odd  t: write part[w][c][l], read part[s][w][lc]
// For every slot, its step-(t+1) writer IS its step-t reader (same wave), so
// the write-after-read hazard is covered by program order; the single
// lgkm-only barrier covers write->read within the step. Values and reduce
// order ((p0+p1)+p2)+p3 are identical to round 13. cur2 via second kernel.

#define BARRIER_LGKM \
    asm volatile("s_waitcnt lgkmcnt(0)\n\ts_barrier" ::: "memory");

__launch_bounds__(256, 1)
__global__ void rsnn_kernel(const float* __restrict__ X,
                            const float* __restrict__ W1,
                            const float* __restrict__ b1,
                            const float* __restrict__ Wrec,
                            const float* __restrict__ brec,
                            float* __restrict__ out_spk) {
#pragma clang fp contract(off)
    __shared__ float WT2[NHID * ROWF];   // 160,000 B
    __shared__ float part[4][4][50];     //   3,200 B

    const int tid = threadIdx.x;
    const int l   = tid & 63;            // lane
    const int w   = tid >> 6;            // wave id = source & output word id
    const int b   = blockIdx.x;

    // ---- stage Wrec (permuted transpose) into LDS ----
    for (int idx = tid; idx < NHID * NHID; idx += 256) {
        int r  = idx / NHID;             // Wrec row  (output neuron)
        int i  = idx - r * NHID;         // Wrec col  (source neuron)
        int lo = r % 50, k = r / 50;
        WT2[i * ROWF + lo * 4 + k] = Wrec[idx];
    }
    __syncthreads();

    const int lc = (l < 50) ? l : 49;    // lanes 50-63 duplicate lane 49
    const int oc = 50 * w + lc;          // this lane's output neuron
    const float w10 = W1[oc * 3 + 0], w11 = W1[oc * 3 + 1], w12 = W1[oc * 3 + 2];
    const float b1j = b1[oc], brj = brec[oc];

    float mem = 0.f;
    unsigned long long bm = 0;           // own word's spike mask

    const float* xp = X + (size_t)b * 3;
    float x0 = xp[0], x1 = xp[1], x2 = xp[2];

    const float* ldsrow  = WT2 + (size_t)lc * 4;
    const int    wbase   = 50 * w;
    float*       spk_out = out_spk + (size_t)b * NHID + wbase + lc;

#define REC_WORD(MASK, BASE)                                                          \
    {                                                                                 \
        unsigned long long m = (MASK);                                                \
        while (m) {                                                                   \
            int i0 = __builtin_ctzll(m); m &= m - 1;                                  \
            bool h1 = m != 0; int i1 = h1 ? __builtin_ctzll(m) : i0; if (h1) m &= m - 1; \
            bool h2 = m != 0; int i2 = h2 ? __builtin_ctzll(m) : i0; if (h2) m &= m - 1; \
            bool h3 = m != 0; int i3 = h3 ? __builtin_ctzll(m) : i0; if (h3) m &= m - 1; \
            const float4 v0 = *(const float4*)(ldsrow + (i0 + (BASE)) * ROWF);        \
            const float4 v1 = *(const float4*)(ldsrow + (i1 + (BASE)) * ROWF);        \
            const float4 v2 = *(const float4*)(ldsrow + (i2 + (BASE)) * ROWF);        \
            const float4 v3 = *(const float4*)(ldsrow + (i3 + (BASE)) * ROWF);        \
            pr0 += v0.x; pr1 += v0.y; pr2 += v0.z; pr3 += v0.w;                       \
            if (h1) { pr0 += v1.x; pr1 += v1.y; pr2 += v1.z; pr3 += v1.w; }           \
            if (h2) { pr0 += v2.x; pr1 += v2.y; pr2 += v2.z; pr3 += v2.w; }           \
            if (h3) { pr0 += v3.x; pr1 += v3.y; pr2 += v3.z; pr3 += v3.w; }           \
        }                                                                             \
    }

// One time step. WRITES/READS select the parity-transposed layout.
#define STEP(T, WR0, WR1, WR2, WR3, RD0, RD1, RD2, RD3)                  \
    {                                                                    \
        const int t = (T);                                               \
        int   tn  = (t + 1 < T_STEPS) ? t + 1 : t;                       \
        float nx0 = xp[(size_t)tn * BATCH * 3 + 0];                      \
        float nx1 = xp[(size_t)tn * BATCH * 3 + 1];                      \
        float nx2 = xp[(size_t)tn * BATCH * 3 + 2];                      \
                                                                         \
        float pr0 = 0.f, pr1 = 0.f, pr2 = 0.f, pr3 = 0.f;                \
        REC_WORD(bm, wbase)                                              \
                                                                         \
        if (l < 50) { WR0 = pr0; WR1 = pr1; WR2 = pr2; WR3 = pr3; }      \
        BARRIER_LGKM                                                     \
                                                                         \
        float p0 = RD0, p1 = RD1, p2 = RD2, p3 = RD3;                    \
        float rec = ((p0 + p1) + p2) + p3;                               \
                                                                         \
        float c1 = fmaf(x2, w12, fmaf(x1, w11, x0 * w10)) + b1j;         \
        float ba = ((BETA_C * mem + c1) + rec) + brj;                    \
        float nm = (mem > THR_C) ? 0.f : ba;                             \
        float sp = (nm > THR_C) ? 1.f : 0.f;                             \
        mem = nm;                                                        \
                                                                         \
        if (l < 50)                                                      \
            spk_out[(size_t)t * BATCH * NHID] = sp;                      \
        bm = __ballot((l < 50) && (sp > 0.5f));                          \
                                                                         \
        x0 = nx0; x1 = nx1; x2 = nx2;                                    \
    }

    for (int tt = 0; tt < T_STEPS; tt += 2) {
        // even step: write part[c][w], read part[w][s]
        STEP(tt,
             part[0][w][l], part[1][w][l], part[2][w][l], part[3][w][l],
             part[w][0][lc], part[w][1][lc], part[w][2][lc], part[w][3][lc])
        // odd step: write part[w][c], read part[s][w]
        STEP(tt + 1,
             part[w][0][l], part[w][1][l], part[w][2][l], part[w][3][l],
             part[0][w][lc], part[1][w][lc], part[2][w][lc], part[3][w][lc])
    }
#undef STEP
#undef REC_WORD
}

// cur2[t,b] = sum_j spk[t,b,j]*W2[j] + b2 — recomputed from stored spikes
// (L3-resident). Terminal output: tree reduction order is safe.
__launch_bounds__(256)
__global__ void cur2_kernel(const float* __restrict__ spk,
                            const float* __restrict__ W2,
                            const float* __restrict__ b2,
                            float* __restrict__ out) {
    const int lane = threadIdx.x & 63;
    const int wid  = (int)((blockIdx.x * blockDim.x + threadIdx.x) >> 6);
    const int nw   = (int)((gridDim.x * blockDim.x) >> 6);

    float4 w2v = {0.f, 0.f, 0.f, 0.f};
    if (lane < 50) w2v = *(const float4*)(W2 + lane * 4);
    const float b2v = b2[0];

    for (int p = wid; p < T_STEPS * BATCH; p += nw) {
        float4 sv = {0.f, 0.f, 0.f, 0.f};
        if (lane < 50) sv = *(const float4*)(spk + (size_t)p * NHID + lane * 4);
        float a = fmaf(sv.w, w2v.w, fmaf(sv.z, w2v.z,
                  fmaf(sv.y, w2v.y, sv.x * w2v.x)));
#pragma unroll
        for (int o = 32; o >= 1; o >>= 1) a += __shfl_xor(a, o);
        if (lane == 0) out[p] = a + b2v;   // p = t*BATCH + b
    }
}

extern "C" void kernel_launch(void* const* d_in, const int* in_sizes, int n_in,
                              void* d_out, int out_size, void* d_ws, size_t ws_size,
                              hipStream_t stream) {
    const float* X    = (const float*)d_in[0];
    const float* W1   = (const float*)d_in[1];
    const float* b1   = (const float*)d_in[2];
    const float* Wrec = (const float*)d_in[3];
    const float* brec = (const float*)d_in[4];
    const float* W2   = (const float*)d_in[5];
    const float* b2   = (const float*)d_in[6];

    float* out_cur2 = (float*)d_out;                            // [T,B,1] flat
    float* out_spk  = (float*)d_out + (size_t)T_STEPS * BATCH;  // [T,B,200] flat

    rsnn_kernel<<<BATCH, 256, 0, stream>>>(X, W1, b1, Wrec, brec, out_spk);
    cur2_kernel<<<1024, 256, 0, stream>>>(out_spk, W2, b2, out_cur2);
}